// Round 8
// baseline (228.134 us; speedup 1.0000x reference)
//
#include <hip/hip_runtime.h>

// Problem constants: B=16, K=8, C=64, L=2048
#define BB 16
#define KK 8
#define CC 64
#define LL 2048

constexpr int CL = CC * LL;               // 131072 elems per batch
constexpr int NELEM = BB * CL;            // 2,097,152
constexpr int WTILE = 256;                // elems per wave tile
constexpr int WPB = 4;                    // waves per block
constexpr int TPB = 256;
constexpr int BTILE = WTILE * WPB;        // 1024 elems per block
constexpr int NBLOCKS = NELEM / BTILE;    // 2048 blocks

#define SIG_OFF 0.11920292202211755f      // 1 - sigmoid(2) = sigmoid(-2)
#define LOG_EPS -16.11809565095832f       // logf(1e-7)

__device__ __forceinline__ float frcp(float x) { return __builtin_amdgcn_rcpf(x); }

// Async global->LDS DMA, 16 B/lane, one instr stages 1 KB (a whole wave tile
// of one stream). No destination VGPR -> register allocator can't sink it.
__device__ __forceinline__ void load_to_lds16(const float* g, float* l) {
    __builtin_amdgcn_global_load_lds(
        (const __attribute__((address_space(1))) void*)g,
        (__attribute__((address_space(3))) void*)l,
        16, 0, 0);
}

// Per-wave drain of THIS WAVE's outstanding DMAs. vmcnt is per-wave state, so
// no __syncthreads is needed: each wave runs its own free pipeline (R6/R7's
// barrier forced vmcnt(0) across all waves each k -> convoy stalls).
__device__ __forceinline__ void wait_vm0() {
    asm volatile("s_waitcnt vmcnt(0)" ::: "memory");
}

__global__ void init_sldj_kernel(const float* __restrict__ sldj_in,
                                 float* __restrict__ sldj_out) {
    int i = threadIdx.x;
    if (i < BB) sldj_out[i] = sldj_in[i];
}

__global__ __launch_bounds__(256) void coupling_kernel(
    const float* __restrict__ x,
    const float* __restrict__ a,
    const float* __restrict__ bv,
    const float* __restrict__ pi,
    const float* __restrict__ mu,
    const float* __restrict__ s,
    float* __restrict__ out,
    float* __restrict__ sldj_out) {

    // Per-wave private region: 9*256 floats = 9 KB
    //   [0..255]=x [256..511]=a [512..767]=b
    //   kbuf0 at 768  (pi|mu|s, 256 each)
    //   kbuf1 at 1536
    __shared__ float lds[WPB][9 * WTILE];   // 36 KB -> 4 blocks/CU
    __shared__ float wsum[WPB];

    const int tid  = threadIdx.x;
    const int lane = tid & 63;
    const int wv   = tid >> 6;
    float* W = lds[wv];
    const int l4 = lane * 4;                // float idx; byte off = lane*16

    const int wbase = blockIdx.x * BTILE + wv * WTILE;  // wave's elem base
    const int b     = wbase >> 17;                      // / CL
    const int kb0   = (b << 20) + (wbase & (CL - 1));   // b*K*CL + rem

    // ---- Prologue: stage x,a,b and k=0 (6 DMA instrs), one wait ----
    load_to_lds16(x  + wbase + l4, &W[0 * WTILE + l4]);
    load_to_lds16(a  + wbase + l4, &W[1 * WTILE + l4]);
    load_to_lds16(bv + wbase + l4, &W[2 * WTILE + l4]);
    load_to_lds16(pi + kb0 + l4, &W[3 * WTILE + l4]);
    load_to_lds16(mu + kb0 + l4, &W[4 * WTILE + l4]);
    load_to_lds16(s  + kb0 + l4, &W[5 * WTILE + l4]);
    wait_vm0();

    const float4 x4 = *(const float4*)&W[0 * WTILE + l4];

    float Spi[4] = {0, 0, 0, 0};
    float Nc [4] = {0, 0, 0, 0};
    float N1 [4] = {0, 0, 0, 0};
    float Np [4] = {0, 0, 0, 0};
    const float xs[4] = {x4.x, x4.y, x4.z, x4.w};

    // ---- Barrier-free per-wave k-pipeline (double-buffered) ----
    for (int k = 0; k < KK; ++k) {
        const int cur = 3 + 3 * (k & 1);
        if (k + 1 < KK) {                   // issue next k's 3 DMAs first
            const int nxt = 3 + 3 * ((k + 1) & 1);
            const int o = kb0 + (k + 1) * CL + l4;
            load_to_lds16(pi + o, &W[nxt * WTILE + l4]);
            load_to_lds16(mu + o, &W[(nxt + 1) * WTILE + l4]);
            load_to_lds16(s  + o, &W[(nxt + 2) * WTILE + l4]);
        }
        // compute k from kbuf[cur] (its data landed before this iteration)
        const float4 p4 = *(const float4*)&W[cur * WTILE + l4];
        const float4 m4 = *(const float4*)&W[(cur + 1) * WTILE + l4];
        const float4 s4 = *(const float4*)&W[(cur + 2) * WTILE + l4];
        const float ps[4] = {p4.x, p4.y, p4.z, p4.w};
        const float ms[4] = {m4.x, m4.y, m4.z, m4.w};
        const float ss[4] = {s4.x, s4.y, s4.z, s4.w};
#pragma unroll
        for (int e = 0; e < 4; ++e) {
            const float invstd = __expf(-ss[e]);
            const float z      = (xs[e] - ms[e]) * invstd;
            const float tt = __expf(-fabsf(z));
            const float r  = frcp(1.f + tt);
            const float tr = tt * r;
            const float sig  = (z >= 0.f) ? r  : tr;
            const float osig = (z >= 0.f) ? tr : r;
            const float ek = __expf(ps[e]);
            Spi[e] += ek;
            Nc [e] += ek * sig;
            N1 [e] += ek * osig;
            Np [e] += ek * invstd * sig * osig;
        }
        if (k + 1 < KK) wait_vm0();         // k+1 landed; next iter may read it
    }

    // ---- Epilogue ----
    const float4 a4 = *(const float4*)&W[1 * WTILE + l4];
    const float4 b4 = *(const float4*)&W[2 * WTILE + l4];
    const float as[4] = {a4.x, a4.y, a4.z, a4.w};
    const float bs[4] = {b4.x, b4.y, b4.z, b4.w};

    float contrib = 0.f;
    float4 o4;
    float* op = (float*)&o4;
#pragma unroll
    for (int e = 0; e < 4; ++e) {
        const float lSpi = __logf(Spi[e]);
        const float lu   = fmaxf(__logf(Nc[e]) - lSpi, LOG_EPS);
        const float lomu = fmaxf(__logf(N1[e]) - lSpi, LOG_EPS);
        const float y        = lu - lomu;    // logit(u)
        const float ldj_term = -lu - lomu;
        const float log_pdf  = __logf(Np[e]) - lSpi;

        const float av = as[e] + 2.f;
        const float t2 = __expf(-fabsf(av));
        const float r2 = frcp(1.f + t2);
        const float sc = ((av >= 0.f) ? r2 : t2 * r2) + SIG_OFF;

        op[e] = (y + bs[e]) * sc;
        contrib += log_pdf + ldj_term + __logf(sc);
    }
    *(float4*)(out + wbase + l4) = o4;

    // block reduction (single barrier, after all per-wave pipelines finish)
#pragma unroll
    for (int off = 32; off > 0; off >>= 1)
        contrib += __shfl_down(contrib, off, 64);
    if (lane == 0) wsum[wv] = contrib;
    __syncthreads();
    if (tid == 0) {
        atomicAdd(&sldj_out[b], wsum[0] + wsum[1] + wsum[2] + wsum[3]);
    }
}

extern "C" void kernel_launch(void* const* d_in, const int* in_sizes, int n_in,
                              void* d_out, int out_size, void* d_ws, size_t ws_size,
                              hipStream_t stream) {
    const float* x    = (const float*)d_in[0];
    const float* a    = (const float*)d_in[1];
    const float* bv   = (const float*)d_in[2];
    const float* pi   = (const float*)d_in[3];
    const float* mu   = (const float*)d_in[4];
    const float* s    = (const float*)d_in[5];
    const float* sldj = (const float*)d_in[6];

    float* out      = (float*)d_out;
    float* sldj_out = out + (size_t)NELEM;  // outputs concat: out, then sldj

    init_sldj_kernel<<<1, 64, 0, stream>>>(sldj, sldj_out);
    coupling_kernel<<<NBLOCKS, TPB, 0, stream>>>(x, a, bv, pi, mu, s, out, sldj_out);
}